// Round 3
// baseline (43203.870 us; speedup 1.0000x reference)
//
#include <hip/hip_runtime.h>
#include <cstdint>
#include <cstddef>

// ---------------------------------------------------------------------------
// RNN_42537356100303: 3-layer tanh RNN (B=128,T=1024,F=24,H=512) + MLP head.
// Phase plan (all on one in-place f16 buffer P[B*T, 512] in ws):
//   k_cvt   : fp32 weights -> f16 (W_hh0..2, W_ih1..2), bias_l = b_ih+b_hh
//   k_xp0   : P = x @ W_ih0^T + bias0            (VALU, K=24)
//   k_scan4 : P[b,t,:] = h_t (in-place over xp), per-batch WG (128 WGs).
//             256 threads / 4 waves / 1 wave-per-SIMD -> 512-VGPR budget.
//             Thread o owns rows {o, o+256}: W cols [0,384) in 96 uint4 of
//             REGISTERS (asm-opaqued so the allocator cannot rematerialize
//             the loads -- rounds 0-2 all silently streamed W from L2, the
//             real bottleneck), cols [384,512) in LDS (stride-33 padded,
//             conflict-free b128). h broadcast from LDS (256 insts/CU).
//             Barrier = lgkmcnt-only + s_barrier, NO sched_barrier (round-2
//             poison) -- global h-store + xp prefetch stay in flight.
//   k_proj  : P = P @ W_ih^T + bias  (in-place row-block MFMA f16 GEMM)
//   k_head  : out = silu(last @ W1^T + b1) @ W2^T + b2
// ---------------------------------------------------------------------------

typedef _Float16 half_t;
typedef __attribute__((ext_vector_type(2))) _Float16 half2_t;
typedef __attribute__((ext_vector_type(8))) _Float16 frag8;
typedef __attribute__((ext_vector_type(4))) float    frag4;

union U32H2 { unsigned u; half2_t h2; };

__device__ __forceinline__ float dot2(unsigned a, unsigned b, float c) {
#if __has_builtin(__builtin_amdgcn_fdot2)
    U32H2 ua; ua.u = a; U32H2 ub; ub.u = b;
    return __builtin_amdgcn_fdot2(ua.h2, ub.h2, c, false);
#else
    U32H2 ua; ua.u = a; U32H2 ub; ub.u = b;
    c += (float)ua.h2.x * (float)ub.h2.x;
    c += (float)ua.h2.y * (float)ub.h2.y;
    return c;
#endif
}

__device__ __forceinline__ float fast_tanh(float x) {
    float ax = __builtin_fabsf(x);
    float e  = __expf(-2.f * ax);          // v_exp_f32 path
    float r  = (1.f - e) / (1.f + e);
    return __builtin_copysignf(r, x);
}

// Barrier that does NOT drain vmcnt: LDS ops ordered (lgkmcnt(0)), global
// stores/loads stay outstanding across steps. No sched_barrier: let the
// scheduler move VALU/loads freely (round-2 lesson).
#define SCAN_BAR() \
    asm volatile("s_waitcnt lgkmcnt(0)\n\ts_barrier" ::: "memory")

#define WN (512 * 512)

// -------------------------------------------------------------- k_cvt ------
__global__ __launch_bounds__(256) void k_cvt(
    const float* whh0, const float* whh1, const float* whh2,
    const float* wih1, const float* wih2,
    const float* bi0, const float* bh0, const float* bi1, const float* bh1,
    const float* bi2, const float* bh2,
    half_t* w16, float* bias)
{
    int idx = blockIdx.x * 256 + threadIdx.x;
    if (idx < 5 * WN) {
        int seg = idx / WN, off = idx % WN;
        const float* s = seg == 0 ? whh0 : seg == 1 ? whh1 : seg == 2 ? whh2
                       : seg == 3 ? wih1 : wih2;
        w16[idx] = (half_t)s[off];
    } else {
        int j = idx - 5 * WN;
        if (j < 3 * 512) {
            int l = j >> 9, o = j & 511;
            const float* a = l == 0 ? bi0 : l == 1 ? bi1 : bi2;
            const float* c = l == 0 ? bh0 : l == 1 ? bh1 : bh2;
            bias[j] = a[o] + c[o];
        }
    }
}

// -------------------------------------------------------------- k_xp0 ------
__global__ __launch_bounds__(256) void k_xp0(
    const float* __restrict__ x, const float* __restrict__ wih0,
    const float* __restrict__ bias0, half_t* __restrict__ P)
{
    __shared__ float wl[512 * 24];
    __shared__ float xl[32 * 25];
    int tid = threadIdx.x;
    int r0  = blockIdx.x * 32;
    for (int i = tid; i < 512 * 24; i += 256) wl[i] = wih0[i];
    for (int i = tid; i < 32 * 24; i += 256) {
        int r = i / 24, f = i % 24;
        xl[r * 25 + f] = x[(size_t)(r0 + r) * 24 + f];
    }
    __syncthreads();
    int r = tid >> 3, c = tid & 7;
    float xr[24];
#pragma unroll
    for (int f = 0; f < 24; f++) xr[f] = xl[r * 25 + f];
    size_t orow = (size_t)(r0 + r) * 512;
    for (int og = 0; og < 8; og++) {
        half_t hv[8];
#pragma unroll
        for (int oj = 0; oj < 8; oj++) {
            int o = og * 64 + c * 8 + oj;
            float acc = bias0[o];
#pragma unroll
            for (int f = 0; f < 24; f++) acc = fmaf(xr[f], wl[o * 24 + f], acc);
            hv[oj] = (half_t)acc;
        }
        *(uint4*)(P + orow + og * 64 + c * 8) = *(const uint4*)hv;
    }
}

// -------------------------------------------------------------- k_scan4 ----
// One WG (256 thr, 4 waves, 1 wave/SIMD -> 512-VGPR budget) per batch.
// Thread o owns output rows {o, o+256}:
//   cols [0,384)   : 96 uint4 in VGPRs (384 regs), asm-opaqued vs remat
//   cols [384,512) : 32 uint4 in LDS at stride 33 (conflict-spread b128)
// h double-buffered in LDS as packed f16 (uniform-address broadcast b128);
// 1 lgkmcnt-only barrier/step; global store + xp prefetch never drained.
__global__ __launch_bounds__(256, 1)
void k_scan4(half_t* __restrict__ P, const half_t* __restrict__ whh)
{
    extern __shared__ char smem[];
    unsigned* hbuf = (unsigned*)smem;               // [2][256] u32  (2 KB)
    uint4*    wlds = (uint4*)(smem + 2048);         // [256*33] uint4 (132 KB)

    int o  = threadIdx.x;                           // 0..255
    int b  = blockIdx.x;
    int r1 = o + 256;

    const uint4* w0 = (const uint4*)(whh + (size_t)o  * 512);  // 64 uint4/row
    const uint4* w1 = (const uint4*)(whh + (size_t)r1 * 512);

    uint4 wreg[96];
#pragma unroll
    for (int g = 0; g < 48; g++) wreg[g]      = w0[g];
#pragma unroll
    for (int g = 0; g < 48; g++) wreg[48 + g] = w1[g];

    uint4* wl = wlds + o * 33;                      // stride 33: bank-spread
#pragma unroll
    for (int j = 0; j < 16; j++) wl[j]      = w0[48 + j];
#pragma unroll
    for (int j = 0; j < 16; j++) wl[16 + j] = w1[48 + j];

    hbuf[o] = 0u; hbuf[256 + o] = 0u;               // h0 = 0 (both buffers)

    // Pin W in registers: outputs of opaque asm are not rematerializable,
    // so the allocator must keep all 384 VGPRs live (budget 512 at 1 w/SIMD).
#pragma unroll
    for (int g = 0; g < 96; g++)
        asm volatile("" : "+v"(wreg[g].x), "+v"(wreg[g].y),
                          "+v"(wreg[g].z), "+v"(wreg[g].w));
    __syncthreads();                                // once; drains init

    half_t* Pb = P + (size_t)b * 1024 * 512;
    _Float16 xa = Pb[o], xb = Pb[r1];               // xp for t = 0

    auto stepf = [&](int t, int tn, const unsigned* hrd, unsigned* hwr)
        __attribute__((always_inline))
    {
        _Float16 xna = Pb[(size_t)tn * 512 + o];    // prefetch next xp
        _Float16 xnb = Pb[(size_t)tn * 512 + r1];
        const uint4* h4 = (const uint4*)hrd;
        float a0 = 0.f, a1 = 0.f, a2 = 0.f, a3 = 0.f;
        float c0 = 0.f, c1 = 0.f, c2 = 0.f, c3 = 0.f;
#pragma unroll
        for (int g = 0; g < 48; g++) {              // register part k<384
            uint4 hv = h4[g];                       // broadcast (uniform addr)
            uint4 wa = wreg[g];
            uint4 wb = wreg[48 + g];
            a0 = dot2(wa.x, hv.x, a0);
            a1 = dot2(wa.y, hv.y, a1);
            a2 = dot2(wa.z, hv.z, a2);
            a3 = dot2(wa.w, hv.w, a3);
            c0 = dot2(wb.x, hv.x, c0);
            c1 = dot2(wb.y, hv.y, c1);
            c2 = dot2(wb.z, hv.z, c2);
            c3 = dot2(wb.w, hv.w, c3);
        }
#pragma unroll
        for (int j = 0; j < 16; j++) {              // LDS part k in [384,512)
            uint4 hv = h4[48 + j];
            uint4 wa = wl[j];
            uint4 wb = wl[16 + j];
            a0 = dot2(wa.x, hv.x, a0);
            a1 = dot2(wa.y, hv.y, a1);
            a2 = dot2(wa.z, hv.z, a2);
            a3 = dot2(wa.w, hv.w, a3);
            c0 = dot2(wb.x, hv.x, c0);
            c1 = dot2(wb.y, hv.y, c1);
            c2 = dot2(wb.z, hv.z, c2);
            c3 = dot2(wb.w, hv.w, c3);
        }
        float ha = fast_tanh((a0 + a1) + (a2 + a3) + (float)xa);
        float hb = fast_tanh((c0 + c1) + (c2 + c3) + (float)xb);
        _Float16 h0 = (_Float16)ha, h1 = (_Float16)hb;
        ((_Float16*)hwr)[o]  = h0;                  // LDS h for next step
        ((_Float16*)hwr)[r1] = h1;
        Pb[(size_t)t * 512 + o]  = h0;              // global, stays in flight
        Pb[(size_t)t * 512 + r1] = h1;
        SCAN_BAR();
        xa = xna; xb = xnb;
    };

    for (int tt = 0; tt < 1024; tt += 2) {
        stepf(tt,     tt + 1,                          hbuf,       hbuf + 256);
        stepf(tt + 1, (tt + 2 < 1024 ? tt + 2 : 1023), hbuf + 256, hbuf);
    }
}

// -------------------------------------------------------------- k_proj -----
// In-place row-block GEMM: rows [r0, r0+64) of P times W^T (W = [512 o][512 k]
// f16), + bias, overwrite. MFMA f32_16x16x32_f16.
__global__ __launch_bounds__(256, 2) void k_proj(
    half_t* __restrict__ P, const half_t* __restrict__ w16,
    const float* __restrict__ bias)
{
    extern __shared__ char smem[];
    half_t* A = (half_t*)smem;                  // 64 rows x stride 520 (65 KB)
    const int AS = 520;
    int tid = threadIdx.x;
    size_t r0 = (size_t)blockIdx.x * 64;

    const uint4* Pg = (const uint4*)(P + r0 * 512);
    for (int u = tid; u < 4096; u += 256) {     // 64 rows x 64 uint4
        uint4 v = Pg[u];
        int row = u >> 6, col = u & 63;
        *(uint4*)(A + row * AS + col * 8) = v;
    }
    __syncthreads();

    int wave = tid >> 6, lane = tid & 63;
    int lm = lane & 15, lq = lane >> 4;

    frag4 acc[4][8];
#pragma unroll
    for (int mt = 0; mt < 4; mt++)
#pragma unroll
        for (int nt = 0; nt < 8; nt++) acc[mt][nt] = (frag4){0.f, 0.f, 0.f, 0.f};

    for (int kb = 0; kb < 16; kb++) {
        int k0 = kb * 32 + lq * 8;
        frag8 af[4];
#pragma unroll
        for (int mt = 0; mt < 4; mt++)
            af[mt] = *(const frag8*)(A + (mt * 16 + lm) * AS + k0);
        frag8 bf[8];
#pragma unroll
        for (int nt = 0; nt < 8; nt++) {
            int n = wave * 128 + nt * 16 + lm;
            bf[nt] = *(const frag8*)(w16 + (size_t)n * 512 + k0);
        }
#pragma unroll
        for (int mt = 0; mt < 4; mt++)
#pragma unroll
            for (int nt = 0; nt < 8; nt++)
                acc[mt][nt] = __builtin_amdgcn_mfma_f32_16x16x32_f16(
                    af[mt], bf[nt], acc[mt][nt], 0, 0, 0);
    }

#pragma unroll
    for (int mt = 0; mt < 4; mt++) {
        int row = mt * 16 + lq * 4;
#pragma unroll
        for (int nt = 0; nt < 8; nt++) {
            int oc = wave * 128 + nt * 16 + lm;
            float bo = bias[oc];
#pragma unroll
            for (int i = 0; i < 4; i++) {
                float v = acc[mt][nt][i] + bo;
                P[(r0 + row + i) * 512 + oc] = (half_t)v;
            }
        }
    }
}

// -------------------------------------------------------------- k_head -----
__global__ __launch_bounds__(256) void k_head(
    const half_t* __restrict__ P, const float* __restrict__ W1,
    const float* __restrict__ b1, const float* __restrict__ W2,
    const float* __restrict__ b2, float* __restrict__ out)
{
    __shared__ float lastv[512];
    __shared__ float zl[1024];
    __shared__ float red[8][33];
    int tid = threadIdx.x, b = blockIdx.x;
    const half_t* lr = P + ((size_t)b * 1024 + 1023) * 512;
    lastv[tid]       = (float)lr[tid];
    lastv[tid + 256] = (float)lr[tid + 256];
    __syncthreads();
#pragma unroll
    for (int i = 0; i < 4; i++) {
        int m = tid + 256 * i;
        const float* wr = W1 + (size_t)m * 512;
        float acc = b1[m];
        for (int k = 0; k < 512; k += 4) {
            float4 wv = *(const float4*)(wr + k);
            acc = fmaf(wv.x, lastv[k],     acc);
            acc = fmaf(wv.y, lastv[k + 1], acc);
            acc = fmaf(wv.z, lastv[k + 2], acc);
            acc = fmaf(wv.w, lastv[k + 3], acc);
        }
        zl[m] = acc / (1.f + __expf(-acc));         // silu
    }
    __syncthreads();
    int c = tid & 7, mc = tid >> 3;                 // 8 outputs x 32 m-chunks
    float p = 0.f;
#pragma unroll
    for (int j = 0; j < 32; j++) {
        int m = mc * 32 + j;
        p = fmaf(zl[m], W2[c * 1024 + m], p);
    }
    red[c][mc] = p;
    __syncthreads();
    if (tid < 8) {
        float s = b2[tid];
#pragma unroll
        for (int j = 0; j < 32; j++) s += red[tid][j];
        out[b * 8 + tid] = s;
    }
}

// ---------------------------------------------------------------------------
extern "C" void kernel_launch(void* const* d_in, const int* in_sizes, int n_in,
                              void* d_out, int out_size, void* d_ws, size_t ws_size,
                              hipStream_t stream)
{
    const float* x    = (const float*)d_in[0];
    const float* wih0 = (const float*)d_in[1];
    const float* whh0 = (const float*)d_in[2];
    const float* bi0  = (const float*)d_in[3];
    const float* bh0  = (const float*)d_in[4];
    const float* wih1 = (const float*)d_in[5];
    const float* whh1 = (const float*)d_in[6];
    const float* bi1  = (const float*)d_in[7];
    const float* bh1  = (const float*)d_in[8];
    const float* wih2 = (const float*)d_in[9];
    const float* whh2 = (const float*)d_in[10];
    const float* bi2  = (const float*)d_in[11];
    const float* bh2  = (const float*)d_in[12];
    const float* W1   = (const float*)d_in[13];
    const float* b1   = (const float*)d_in[14];
    const float* W2   = (const float*)d_in[15];
    const float* b2   = (const float*)d_in[16];
    float* out = (float*)d_out;

    char* ws = (char*)d_ws;
    half_t* P    = (half_t*)ws;                               // 134,217,728 B
    half_t* W16  = (half_t*)(ws + 134217728);                 //   2,621,440 B
    float*  bias = (float*)(ws + 134217728 + 2621440);        //       6,144 B

    // dynamic-LDS opt-in (>64 KB); idempotent, not a stream op
    hipFuncSetAttribute((const void*)k_scan4,
                        hipFuncAttributeMaxDynamicSharedMemorySize, 137216);
    hipFuncSetAttribute((const void*)k_proj,
                        hipFuncAttributeMaxDynamicSharedMemorySize, 66560);

    k_cvt<<<5126, 256, 0, stream>>>(whh0, whh1, whh2, wih1, wih2,
                                    bi0, bh0, bi1, bh1, bi2, bh2, W16, bias);
    k_xp0<<<4096, 256, 0, stream>>>(x, wih0, bias, P);
    k_scan4<<<128, 256, 137216, stream>>>(P, W16 + 0 * WN);
    k_proj<<<2048, 256, 66560, stream>>>(P, W16 + 3 * WN, bias + 512);
    k_scan4<<<128, 256, 137216, stream>>>(P, W16 + 1 * WN);
    k_proj<<<2048, 256, 66560, stream>>>(P, W16 + 4 * WN, bias + 1024);
    k_scan4<<<128, 256, 137216, stream>>>(P, W16 + 2 * WN);
    k_head<<<128, 256, 0, stream>>>(P, W1, b1, W2, b2, out);
}

// Round 4
// 21784.505 us; speedup vs baseline: 1.9832x; 1.9832x over previous
//
#include <hip/hip_runtime.h>
#include <cstdint>
#include <cstddef>

// ---------------------------------------------------------------------------
// RNN_42537356100303: 3-layer tanh RNN (B=128,T=1024,F=24,H=512) + MLP head.
// Phase plan (all on one in-place f16 buffer P[B*T, 512] in ws):
//   k_cvt   : fp32 weights -> f16 (W_hh0..2, W_ih1..2), bias_l = b_ih+b_hh
//   k_xp0   : P = x @ W_ih0^T + bias0            (VALU, K=24)
//   k_scan5 : P[b,t,:] = h_t (in-place over xp). M=2 batches per WG, 64 WGs
//             x 512 thr. Thread o owns W_hh row o, streamed from L2 ONCE per
//             step and used for BOTH batches' dot products -- halves the
//             per-step L2 W-traffic that round-0 analysis proved dominant
//             (16 WG/XCD x 448 KB / 1.8 KB/cyc = 4000 cyc = measured 3960).
//             Now: VALU 2048 cyc vs L2 1700 cyc -> VALU-issue-bound.
//             W cols [384,512) live in LDS (uint4-stride-17: 0 bank
//             conflicts, validated round 3). h (2 batches) double-buffered
//             in LDS. Barrier = lgkmcnt-only asm (validated rounds 2-3);
//             NO register pinning (round-3 lesson: 256 v-reg cap -> scratch
//             catastrophe), NO sched_barrier (round-2 lesson).
//   k_proj  : P = P @ W_ih^T + bias  (in-place row-block MFMA f16 GEMM)
//   k_head  : out = silu(last @ W1^T + b1) @ W2^T + b2
// ---------------------------------------------------------------------------

typedef _Float16 half_t;
typedef __attribute__((ext_vector_type(2))) _Float16 half2_t;
typedef __attribute__((ext_vector_type(8))) _Float16 frag8;
typedef __attribute__((ext_vector_type(4))) float    frag4;

union U32H2 { unsigned u; half2_t h2; };

__device__ __forceinline__ float dot2(unsigned a, unsigned b, float c) {
#if __has_builtin(__builtin_amdgcn_fdot2)
    U32H2 ua; ua.u = a; U32H2 ub; ub.u = b;
    return __builtin_amdgcn_fdot2(ua.h2, ub.h2, c, false);
#else
    U32H2 ua; ua.u = a; U32H2 ub; ub.u = b;
    c += (float)ua.h2.x * (float)ub.h2.x;
    c += (float)ua.h2.y * (float)ub.h2.y;
    return c;
#endif
}

__device__ __forceinline__ float fast_tanh(float x) {
    float ax = __builtin_fabsf(x);
    float e  = __expf(-2.f * ax);          // v_exp_f32 path
    float r  = (1.f - e) / (1.f + e);
    return __builtin_copysignf(r, x);
}

// Barrier that does NOT drain vmcnt: LDS ops ordered (lgkmcnt(0)), global
// stores/loads stay outstanding across steps.
#define SCAN_BAR() \
    asm volatile("s_waitcnt lgkmcnt(0)\n\ts_barrier" ::: "memory")

#define WN (512 * 512)

// -------------------------------------------------------------- k_cvt ------
__global__ __launch_bounds__(256) void k_cvt(
    const float* whh0, const float* whh1, const float* whh2,
    const float* wih1, const float* wih2,
    const float* bi0, const float* bh0, const float* bi1, const float* bh1,
    const float* bi2, const float* bh2,
    half_t* w16, float* bias)
{
    int idx = blockIdx.x * 256 + threadIdx.x;
    if (idx < 5 * WN) {
        int seg = idx / WN, off = idx % WN;
        const float* s = seg == 0 ? whh0 : seg == 1 ? whh1 : seg == 2 ? whh2
                       : seg == 3 ? wih1 : wih2;
        w16[idx] = (half_t)s[off];
    } else {
        int j = idx - 5 * WN;
        if (j < 3 * 512) {
            int l = j >> 9, o = j & 511;
            const float* a = l == 0 ? bi0 : l == 1 ? bi1 : bi2;
            const float* c = l == 0 ? bh0 : l == 1 ? bh1 : bh2;
            bias[j] = a[o] + c[o];
        }
    }
}

// -------------------------------------------------------------- k_xp0 ------
__global__ __launch_bounds__(256) void k_xp0(
    const float* __restrict__ x, const float* __restrict__ wih0,
    const float* __restrict__ bias0, half_t* __restrict__ P)
{
    __shared__ float wl[512 * 24];
    __shared__ float xl[32 * 25];
    int tid = threadIdx.x;
    int r0  = blockIdx.x * 32;
    for (int i = tid; i < 512 * 24; i += 256) wl[i] = wih0[i];
    for (int i = tid; i < 32 * 24; i += 256) {
        int r = i / 24, f = i % 24;
        xl[r * 25 + f] = x[(size_t)(r0 + r) * 24 + f];
    }
    __syncthreads();
    int r = tid >> 3, c = tid & 7;
    float xr[24];
#pragma unroll
    for (int f = 0; f < 24; f++) xr[f] = xl[r * 25 + f];
    size_t orow = (size_t)(r0 + r) * 512;
    for (int og = 0; og < 8; og++) {
        half_t hv[8];
#pragma unroll
        for (int oj = 0; oj < 8; oj++) {
            int o = og * 64 + c * 8 + oj;
            float acc = bias0[o];
#pragma unroll
            for (int f = 0; f < 24; f++) acc = fmaf(xr[f], wl[o * 24 + f], acc);
            hv[oj] = (half_t)acc;
        }
        *(uint4*)(P + orow + og * 64 + c * 8) = *(const uint4*)hv;
    }
}

// -------------------------------------------------------------- k_scan5 ----
// One WG (512 thr) per PAIR of batches. Thread o owns W_hh row o:
//   cols [0,384)   : streamed from L2 each step (48 uint4), reused for both
//                    batches (the M=2 amortization)
//   cols [384,512) : 16 uint4 in LDS, uint4-stride-17 (conflict-free b128)
// h: [2 bufs][2 batches][512 f16] in LDS, broadcast b128 reads.
__global__ __launch_bounds__(512)
void k_scan5(half_t* __restrict__ P, const half_t* __restrict__ whh)
{
    extern __shared__ char smem[];
    unsigned* hbuf = (unsigned*)smem;               // [2][2][256] u32 (4 KB)
    uint4*    wlds = (uint4*)(smem + 4096);         // [512*17] uint4 (136 KB)

    int o = threadIdx.x;                            // 0..511 = W row
    int g = blockIdx.x;                             // batch pair
    int b0 = 2 * g, b1 = 2 * g + 1;

    const uint4* wrow = (const uint4*)(whh + (size_t)o * 512);  // 64 uint4/row

    uint4* wl = wlds + o * 17;                      // stride 17: bank-uniform
#pragma unroll
    for (int j = 0; j < 16; j++) wl[j] = wrow[48 + j];
    hbuf[o] = 0u; hbuf[512 + o] = 0u;               // h0 = 0 (both buffers)
    __syncthreads();                                // once; drains init

    half_t* PA = P + (size_t)b0 * 1024 * 512;
    half_t* PB = P + (size_t)b1 * 1024 * 512;
    _Float16 xa = PA[o], xb = PB[o];                // xp for t = 0

    auto stepf = [&](int t, int tn, const unsigned* rd, unsigned* wr)
        __attribute__((always_inline))
    {
        _Float16 xna = PA[(size_t)tn * 512 + o];    // prefetch next xp
        _Float16 xnb = PB[(size_t)tn * 512 + o];
        const uint4* hA4 = (const uint4*)rd;        // batch A h (broadcast)
        const uint4* hB4 = (const uint4*)(rd + 256);// batch B h
        float a0 = 0.f, a1 = 0.f, a2 = 0.f, a3 = 0.f;
        float c0 = 0.f, c1 = 0.f, c2 = 0.f, c3 = 0.f;
#pragma unroll
        for (int k = 0; k < 48; k++) {              // streamed part k<384
            uint4 wv = wrow[k];                     // L2 stream, reused x2
            uint4 ha = hA4[k];
            uint4 hb = hB4[k];
            a0 = dot2(wv.x, ha.x, a0);
            a1 = dot2(wv.y, ha.y, a1);
            a2 = dot2(wv.z, ha.z, a2);
            a3 = dot2(wv.w, ha.w, a3);
            c0 = dot2(wv.x, hb.x, c0);
            c1 = dot2(wv.y, hb.y, c1);
            c2 = dot2(wv.z, hb.z, c2);
            c3 = dot2(wv.w, hb.w, c3);
        }
#pragma unroll
        for (int j = 0; j < 16; j++) {              // LDS part k in [384,512)
            uint4 wv = wl[j];
            uint4 ha = hA4[48 + j];
            uint4 hb = hB4[48 + j];
            a0 = dot2(wv.x, ha.x, a0);
            a1 = dot2(wv.y, ha.y, a1);
            a2 = dot2(wv.z, ha.z, a2);
            a3 = dot2(wv.w, ha.w, a3);
            c0 = dot2(wv.x, hb.x, c0);
            c1 = dot2(wv.y, hb.y, c1);
            c2 = dot2(wv.z, hb.z, c2);
            c3 = dot2(wv.w, hb.w, c3);
        }
        float ha = fast_tanh((a0 + a1) + (a2 + a3) + (float)xa);
        float hb = fast_tanh((c0 + c1) + (c2 + c3) + (float)xb);
        _Float16 h0 = (_Float16)ha, h1 = (_Float16)hb;
        ((_Float16*)wr)[o]         = h0;            // LDS h for next step
        ((_Float16*)(wr + 256))[o] = h1;
        PA[(size_t)t * 512 + o] = h0;               // global, stays in flight
        PB[(size_t)t * 512 + o] = h1;
        SCAN_BAR();
        xa = xna; xb = xnb;
    };

    for (int tt = 0; tt < 1024; tt += 2) {
        stepf(tt,     tt + 1,                          hbuf,       hbuf + 512);
        stepf(tt + 1, (tt + 2 < 1024 ? tt + 2 : 1023), hbuf + 512, hbuf);
    }
}

// -------------------------------------------------------------- k_proj -----
// In-place row-block GEMM: rows [r0, r0+64) of P times W^T (W = [512 o][512 k]
// f16), + bias, overwrite. MFMA f32_16x16x32_f16.
__global__ __launch_bounds__(256, 2) void k_proj(
    half_t* __restrict__ P, const half_t* __restrict__ w16,
    const float* __restrict__ bias)
{
    extern __shared__ char smem[];
    half_t* A = (half_t*)smem;                  // 64 rows x stride 520 (65 KB)
    const int AS = 520;
    int tid = threadIdx.x;
    size_t r0 = (size_t)blockIdx.x * 64;

    const uint4* Pg = (const uint4*)(P + r0 * 512);
    for (int u = tid; u < 4096; u += 256) {     // 64 rows x 64 uint4
        uint4 v = Pg[u];
        int row = u >> 6, col = u & 63;
        *(uint4*)(A + row * AS + col * 8) = v;
    }
    __syncthreads();

    int wave = tid >> 6, lane = tid & 63;
    int lm = lane & 15, lq = lane >> 4;

    frag4 acc[4][8];
#pragma unroll
    for (int mt = 0; mt < 4; mt++)
#pragma unroll
        for (int nt = 0; nt < 8; nt++) acc[mt][nt] = (frag4){0.f, 0.f, 0.f, 0.f};

    for (int kb = 0; kb < 16; kb++) {
        int k0 = kb * 32 + lq * 8;
        frag8 af[4];
#pragma unroll
        for (int mt = 0; mt < 4; mt++)
            af[mt] = *(const frag8*)(A + (mt * 16 + lm) * AS + k0);
        frag8 bf[8];
#pragma unroll
        for (int nt = 0; nt < 8; nt++) {
            int n = wave * 128 + nt * 16 + lm;
            bf[nt] = *(const frag8*)(w16 + (size_t)n * 512 + k0);
        }
#pragma unroll
        for (int mt = 0; mt < 4; mt++)
#pragma unroll
            for (int nt = 0; nt < 8; nt++)
                acc[mt][nt] = __builtin_amdgcn_mfma_f32_16x16x32_f16(
                    af[mt], bf[nt], acc[mt][nt], 0, 0, 0);
    }

#pragma unroll
    for (int mt = 0; mt < 4; mt++) {
        int row = mt * 16 + lq * 4;
#pragma unroll
        for (int nt = 0; nt < 8; nt++) {
            int oc = wave * 128 + nt * 16 + lm;
            float bo = bias[oc];
#pragma unroll
            for (int i = 0; i < 4; i++) {
                float v = acc[mt][nt][i] + bo;
                P[(r0 + row + i) * 512 + oc] = (half_t)v;
            }
        }
    }
}

// -------------------------------------------------------------- k_head -----
__global__ __launch_bounds__(256) void k_head(
    const half_t* __restrict__ P, const float* __restrict__ W1,
    const float* __restrict__ b1, const float* __restrict__ W2,
    const float* __restrict__ b2, float* __restrict__ out)
{
    __shared__ float lastv[512];
    __shared__ float zl[1024];
    __shared__ float red[8][33];
    int tid = threadIdx.x, b = blockIdx.x;
    const half_t* lr = P + ((size_t)b * 1024 + 1023) * 512;
    lastv[tid]       = (float)lr[tid];
    lastv[tid + 256] = (float)lr[tid + 256];
    __syncthreads();
#pragma unroll
    for (int i = 0; i < 4; i++) {
        int m = tid + 256 * i;
        const float* wr = W1 + (size_t)m * 512;
        float acc = b1[m];
        for (int k = 0; k < 512; k += 4) {
            float4 wv = *(const float4*)(wr + k);
            acc = fmaf(wv.x, lastv[k],     acc);
            acc = fmaf(wv.y, lastv[k + 1], acc);
            acc = fmaf(wv.z, lastv[k + 2], acc);
            acc = fmaf(wv.w, lastv[k + 3], acc);
        }
        zl[m] = acc / (1.f + __expf(-acc));         // silu
    }
    __syncthreads();
    int c = tid & 7, mc = tid >> 3;                 // 8 outputs x 32 m-chunks
    float p = 0.f;
#pragma unroll
    for (int j = 0; j < 32; j++) {
        int m = mc * 32 + j;
        p = fmaf(zl[m], W2[c * 1024 + m], p);
    }
    red[c][mc] = p;
    __syncthreads();
    if (tid < 8) {
        float s = b2[tid];
#pragma unroll
        for (int j = 0; j < 32; j++) s += red[tid][j];
        out[b * 8 + tid] = s;
    }
}

// ---------------------------------------------------------------------------
extern "C" void kernel_launch(void* const* d_in, const int* in_sizes, int n_in,
                              void* d_out, int out_size, void* d_ws, size_t ws_size,
                              hipStream_t stream)
{
    const float* x    = (const float*)d_in[0];
    const float* wih0 = (const float*)d_in[1];
    const float* whh0 = (const float*)d_in[2];
    const float* bi0  = (const float*)d_in[3];
    const float* bh0  = (const float*)d_in[4];
    const float* wih1 = (const float*)d_in[5];
    const float* whh1 = (const float*)d_in[6];
    const float* bi1  = (const float*)d_in[7];
    const float* bh1  = (const float*)d_in[8];
    const float* wih2 = (const float*)d_in[9];
    const float* whh2 = (const float*)d_in[10];
    const float* bi2  = (const float*)d_in[11];
    const float* bh2  = (const float*)d_in[12];
    const float* W1   = (const float*)d_in[13];
    const float* b1   = (const float*)d_in[14];
    const float* W2   = (const float*)d_in[15];
    const float* b2   = (const float*)d_in[16];
    float* out = (float*)d_out;

    char* ws = (char*)d_ws;
    half_t* P    = (half_t*)ws;                               // 134,217,728 B
    half_t* W16  = (half_t*)(ws + 134217728);                 //   2,621,440 B
    float*  bias = (float*)(ws + 134217728 + 2621440);        //       6,144 B

    // dynamic-LDS opt-in (>64 KB); idempotent, not a stream op
    hipFuncSetAttribute((const void*)k_scan5,
                        hipFuncAttributeMaxDynamicSharedMemorySize, 143360);
    hipFuncSetAttribute((const void*)k_proj,
                        hipFuncAttributeMaxDynamicSharedMemorySize, 66560);

    k_cvt<<<5126, 256, 0, stream>>>(whh0, whh1, whh2, wih1, wih2,
                                    bi0, bh0, bi1, bh1, bi2, bh2, W16, bias);
    k_xp0<<<4096, 256, 0, stream>>>(x, wih0, bias, P);
    k_scan5<<<64, 512, 143360, stream>>>(P, W16 + 0 * WN);
    k_proj<<<2048, 256, 66560, stream>>>(P, W16 + 3 * WN, bias + 512);
    k_scan5<<<64, 512, 143360, stream>>>(P, W16 + 1 * WN);
    k_proj<<<2048, 256, 66560, stream>>>(P, W16 + 4 * WN, bias + 1024);
    k_scan5<<<64, 512, 143360, stream>>>(P, W16 + 2 * WN);
    k_head<<<128, 256, 0, stream>>>(P, W1, b1, W2, b2, out);
}

// Round 6
// 10243.340 us; speedup vs baseline: 4.2178x; 2.1267x over previous
//
#include <hip/hip_runtime.h>
#include <cstdint>
#include <cstddef>

// ---------------------------------------------------------------------------
// RNN_42537356100303: 3-layer tanh RNN (B=128,T=1024,F=24,H=512) + MLP head.
// Phase plan (all on one in-place f16 buffer P[B*T, 512] in ws):
//   k_cvt   : fp32 weights -> f16 (W_hh0..2, W_ih1..2), bias_l = b_ih+b_hh
//   k_xp0   : P = x @ W_ih0^T + bias0            (VALU, K=24)
//   k_scan7 : P[b,t,:] = h_t (in-place over xp), per-batch WG (128 WGs x 512).
//             Validated model (rounds 0/4): step cost == per-CU W-delivery,
//             448 KB / 113 B/cyc ~= 4000 cyc == round-0's 3960. Fix = W
//             residency on-CU, sized to the 256 addressable-VGPR cap:
//               40 uint4 (160 regs) PINNED: plain C++ loads + "+v" identity
//                  asm (round-3 mechanism, crash-free; round-5's raw asm
//                  global_load crashed -- pin VALUES, never emit VMEM asm)
//               10 uint4 -> LDS stride-11-uint4 (even-dword stride class
//                  measured 0 conflicts in rounds 3/4); 92 KB LDS also
//                  forces 1 WG/CU so per-CU W traffic can't double
//               14 uint4 streamed from L2 (~112 KB/CU/step ~= 1000 cyc)
//             h double-buffered in LDS (broadcast b128). Barrier =
//             lgkmcnt-only asm (validated rounds 2-4), NO sched_barrier.
//   k_proj  : P = P @ W_ih^T + bias  (in-place row-block MFMA f16 GEMM)
//   k_head  : out = silu(last @ W1^T + b1) @ W2^T + b2
// ---------------------------------------------------------------------------

typedef _Float16 half_t;
typedef __attribute__((ext_vector_type(2))) _Float16 half2_t;
typedef __attribute__((ext_vector_type(8))) _Float16 frag8;
typedef __attribute__((ext_vector_type(4))) float    frag4;

union U32H2 { unsigned u; half2_t h2; };

__device__ __forceinline__ float dot2(unsigned a, unsigned b, float c) {
#if __has_builtin(__builtin_amdgcn_fdot2)
    U32H2 ua; ua.u = a; U32H2 ub; ub.u = b;
    return __builtin_amdgcn_fdot2(ua.h2, ub.h2, c, false);
#else
    U32H2 ua; ua.u = a; U32H2 ub; ub.u = b;
    c += (float)ua.h2.x * (float)ub.h2.x;
    c += (float)ua.h2.y * (float)ub.h2.y;
    return c;
#endif
}

__device__ __forceinline__ float fast_tanh(float x) {
    float ax = __builtin_fabsf(x);
    float e  = __expf(-2.f * ax);          // v_exp_f32 path
    float r  = (1.f - e) / (1.f + e);
    return __builtin_copysignf(r, x);
}

// Barrier that does NOT drain vmcnt: LDS ops ordered (lgkmcnt(0)), global
// stores/loads stay outstanding across steps.
#define SCAN_BAR() \
    asm volatile("s_waitcnt lgkmcnt(0)\n\ts_barrier" ::: "memory")

#define WN (512 * 512)

// W row split (uint4 units): [0,NREG) pinned regs, [NREG,NREG+NSTR) streamed,
// [NREG+NSTR, 64) in LDS.
#define NREG 40
#define NSTR 14
#define NLDS 10
#define WSTRIDE 11   // LDS row stride in uint4 (even-dword class, 0-conflict)

// -------------------------------------------------------------- k_cvt ------
__global__ __launch_bounds__(256) void k_cvt(
    const float* whh0, const float* whh1, const float* whh2,
    const float* wih1, const float* wih2,
    const float* bi0, const float* bh0, const float* bi1, const float* bh1,
    const float* bi2, const float* bh2,
    half_t* w16, float* bias)
{
    int idx = blockIdx.x * 256 + threadIdx.x;
    if (idx < 5 * WN) {
        int seg = idx / WN, off = idx % WN;
        const float* s = seg == 0 ? whh0 : seg == 1 ? whh1 : seg == 2 ? whh2
                       : seg == 3 ? wih1 : wih2;
        w16[idx] = (half_t)s[off];
    } else {
        int j = idx - 5 * WN;
        if (j < 3 * 512) {
            int l = j >> 9, o = j & 511;
            const float* a = l == 0 ? bi0 : l == 1 ? bi1 : bi2;
            const float* c = l == 0 ? bh0 : l == 1 ? bh1 : bh2;
            bias[j] = a[o] + c[o];
        }
    }
}

// -------------------------------------------------------------- k_xp0 ------
__global__ __launch_bounds__(256) void k_xp0(
    const float* __restrict__ x, const float* __restrict__ wih0,
    const float* __restrict__ bias0, half_t* __restrict__ P)
{
    __shared__ float wl[512 * 24];
    __shared__ float xl[32 * 25];
    int tid = threadIdx.x;
    int r0  = blockIdx.x * 32;
    for (int i = tid; i < 512 * 24; i += 256) wl[i] = wih0[i];
    for (int i = tid; i < 32 * 24; i += 256) {
        int r = i / 24, f = i % 24;
        xl[r * 25 + f] = x[(size_t)(r0 + r) * 24 + f];
    }
    __syncthreads();
    int r = tid >> 3, c = tid & 7;
    float xr[24];
#pragma unroll
    for (int f = 0; f < 24; f++) xr[f] = xl[r * 25 + f];
    size_t orow = (size_t)(r0 + r) * 512;
    for (int og = 0; og < 8; og++) {
        half_t hv[8];
#pragma unroll
        for (int oj = 0; oj < 8; oj++) {
            int o = og * 64 + c * 8 + oj;
            float acc = bias0[o];
#pragma unroll
            for (int f = 0; f < 24; f++) acc = fmaf(xr[f], wl[o * 24 + f], acc);
            hv[oj] = (half_t)acc;
        }
        *(uint4*)(P + orow + og * 64 + c * 8) = *(const uint4*)hv;
    }
}

// -------------------------------------------------------------- k_scan7 ----
// One WG (512 thr, 8 waves, 2 waves/SIMD -> 256-VGPR budget) per batch.
// Thread o owns W row o: 40 uint4 pinned VGPR + 10 uint4 LDS + 14 streamed.
// h: [2][256] u32 packed f16 in LDS, uniform-address broadcast b128 reads.
__global__ __launch_bounds__(512, 2)
void k_scan7(half_t* __restrict__ P, const half_t* __restrict__ whh)
{
    extern __shared__ char smem[];
    unsigned* hbuf = (unsigned*)smem;               // [2][256] u32 (2 KB)
    uint4*    wlds = (uint4*)(smem + 2048);         // [512*11] uint4 (90 KB)

    int o = threadIdx.x;                            // 0..511 = W row
    int b = blockIdx.x;

    const uint4* wrow = (const uint4*)(whh + (size_t)o * 512);  // 64 uint4

    // Held part: PLAIN loads (compiler-managed vmcnt) ...
    uint4 wreg[NREG];
#pragma unroll
    for (int g = 0; g < NREG; g++) wreg[g] = wrow[g];

    uint4* wl = wlds + o * WSTRIDE;
#pragma unroll
    for (int j = 0; j < NLDS; j++) wl[j] = wrow[NREG + NSTR + j];
    hbuf[o] = 0u;                                   // both h buffers = 0

    // ... then pin: identity-asm outputs are not rematerializable, so the
    // allocator must keep the 160 VGPRs live (160 + ~70 working < 256 cap;
    // round-3 mechanism, crash-free; round-3's failure was sizing at 384).
#pragma unroll
    for (int g = 0; g < NREG; g++)
        asm volatile("" : "+v"(wreg[g].x), "+v"(wreg[g].y),
                          "+v"(wreg[g].z), "+v"(wreg[g].w));
    __syncthreads();                                // once; drains init

    half_t* Pb = P + (size_t)b * 1024 * 512;
    _Float16 xph = Pb[o];                           // xp for t = 0

    auto stepf = [&](int t, int tn, const unsigned* hrd, unsigned* hwr)
        __attribute__((always_inline))
    {
        _Float16 xpn = Pb[(size_t)tn * 512 + o];    // prefetch next xp
        const uint4* h4 = (const uint4*)hrd;        // broadcast reads
        float a0 = 0.f, a1 = 0.f, a2 = 0.f, a3 = 0.f;
#pragma unroll
        for (int j = 0; j < NSTR; j++) {            // L2-streamed part
            uint4 hv = h4[NREG + j];
            uint4 wv = wrow[NREG + j];
            a0 = dot2(wv.x, hv.x, a0);
            a1 = dot2(wv.y, hv.y, a1);
            a2 = dot2(wv.z, hv.z, a2);
            a3 = dot2(wv.w, hv.w, a3);
        }
#pragma unroll
        for (int g = 0; g < NREG; g++) {            // register-resident part
            uint4 hv = h4[g];
            uint4 wv = wreg[g];
            a0 = dot2(wv.x, hv.x, a0);
            a1 = dot2(wv.y, hv.y, a1);
            a2 = dot2(wv.z, hv.z, a2);
            a3 = dot2(wv.w, hv.w, a3);
        }
#pragma unroll
        for (int j = 0; j < NLDS; j++) {            // LDS-resident part
            uint4 hv = h4[NREG + NSTR + j];
            uint4 wv = wl[j];
            a0 = dot2(wv.x, hv.x, a0);
            a1 = dot2(wv.y, hv.y, a1);
            a2 = dot2(wv.z, hv.z, a2);
            a3 = dot2(wv.w, hv.w, a3);
        }
        float hn = fast_tanh((a0 + a1) + (a2 + a3) + (float)xph);
        _Float16 hh = (_Float16)hn;
        ((_Float16*)hwr)[o] = hh;                   // LDS h for next step
        Pb[(size_t)t * 512 + o] = hh;               // global, stays in flight
        SCAN_BAR();
        xph = xpn;
    };

    for (int tt = 0; tt < 1024; tt += 2) {
        stepf(tt,     tt + 1,                          hbuf,       hbuf + 256);
        stepf(tt + 1, (tt + 2 < 1024 ? tt + 2 : 1023), hbuf + 256, hbuf);
    }
}

// -------------------------------------------------------------- k_proj -----
// In-place row-block GEMM: rows [r0, r0+64) of P times W^T (W = [512 o][512 k]
// f16), + bias, overwrite. MFMA f32_16x16x32_f16.
__global__ __launch_bounds__(256, 2) void k_proj(
    half_t* __restrict__ P, const half_t* __restrict__ w16,
    const float* __restrict__ bias)
{
    extern __shared__ char smem[];
    half_t* A = (half_t*)smem;                  // 64 rows x stride 520 (65 KB)
    const int AS = 520;
    int tid = threadIdx.x;
    size_t r0 = (size_t)blockIdx.x * 64;

    const uint4* Pg = (const uint4*)(P + r0 * 512);
    for (int u = tid; u < 4096; u += 256) {     // 64 rows x 64 uint4
        uint4 v = Pg[u];
        int row = u >> 6, col = u & 63;
        *(uint4*)(A + row * AS + col * 8) = v;
    }
    __syncthreads();

    int wave = tid >> 6, lane = tid & 63;
    int lm = lane & 15, lq = lane >> 4;

    frag4 acc[4][8];
#pragma unroll
    for (int mt = 0; mt < 4; mt++)
#pragma unroll
        for (int nt = 0; nt < 8; nt++) acc[mt][nt] = (frag4){0.f, 0.f, 0.f, 0.f};

    for (int kb = 0; kb < 16; kb++) {
        int k0 = kb * 32 + lq * 8;
        frag8 af[4];
#pragma unroll
        for (int mt = 0; mt < 4; mt++)
            af[mt] = *(const frag8*)(A + (mt * 16 + lm) * AS + k0);
        frag8 bf[8];
#pragma unroll
        for (int nt = 0; nt < 8; nt++) {
            int n = wave * 128 + nt * 16 + lm;
            bf[nt] = *(const frag8*)(w16 + (size_t)n * 512 + k0);
        }
#pragma unroll
        for (int mt = 0; mt < 4; mt++)
#pragma unroll
            for (int nt = 0; nt < 8; nt++)
                acc[mt][nt] = __builtin_amdgcn_mfma_f32_16x16x32_f16(
                    af[mt], bf[nt], acc[mt][nt], 0, 0, 0);
    }

#pragma unroll
    for (int mt = 0; mt < 4; mt++) {
        int row = mt * 16 + lq * 4;
#pragma unroll
        for (int nt = 0; nt < 8; nt++) {
            int oc = wave * 128 + nt * 16 + lm;
            float bo = bias[oc];
#pragma unroll
            for (int i = 0; i < 4; i++) {
                float v = acc[mt][nt][i] + bo;
                P[(r0 + row + i) * 512 + oc] = (half_t)v;
            }
        }
    }
}

// -------------------------------------------------------------- k_head -----
__global__ __launch_bounds__(256) void k_head(
    const half_t* __restrict__ P, const float* __restrict__ W1,
    const float* __restrict__ b1, const float* __restrict__ W2,
    const float* __restrict__ b2, float* __restrict__ out)
{
    __shared__ float lastv[512];
    __shared__ float zl[1024];
    __shared__ float red[8][33];
    int tid = threadIdx.x, b = blockIdx.x;
    const half_t* lr = P + ((size_t)b * 1024 + 1023) * 512;
    lastv[tid]       = (float)lr[tid];
    lastv[tid + 256] = (float)lr[tid + 256];
    __syncthreads();
#pragma unroll
    for (int i = 0; i < 4; i++) {
        int m = tid + 256 * i;
        const float* wr = W1 + (size_t)m * 512;
        float acc = b1[m];
        for (int k = 0; k < 512; k += 4) {
            float4 wv = *(const float4*)(wr + k);
            acc = fmaf(wv.x, lastv[k],     acc);
            acc = fmaf(wv.y, lastv[k + 1], acc);
            acc = fmaf(wv.z, lastv[k + 2], acc);
            acc = fmaf(wv.w, lastv[k + 3], acc);
        }
        zl[m] = acc / (1.f + __expf(-acc));         // silu
    }
    __syncthreads();
    int c = tid & 7, mc = tid >> 3;                 // 8 outputs x 32 m-chunks
    float p = 0.f;
#pragma unroll
    for (int j = 0; j < 32; j++) {
        int m = mc * 32 + j;
        p = fmaf(zl[m], W2[c * 1024 + m], p);
    }
    red[c][mc] = p;
    __syncthreads();
    if (tid < 8) {
        float s = b2[tid];
#pragma unroll
        for (int j = 0; j < 32; j++) s += red[tid][j];
        out[b * 8 + tid] = s;
    }
}

// ---------------------------------------------------------------------------
extern "C" void kernel_launch(void* const* d_in, const int* in_sizes, int n_in,
                              void* d_out, int out_size, void* d_ws, size_t ws_size,
                              hipStream_t stream)
{
    const float* x    = (const float*)d_in[0];
    const float* wih0 = (const float*)d_in[1];
    const float* whh0 = (const float*)d_in[2];
    const float* bi0  = (const float*)d_in[3];
    const float* bh0  = (const float*)d_in[4];
    const float* wih1 = (const float*)d_in[5];
    const float* whh1 = (const float*)d_in[6];
    const float* bi1  = (const float*)d_in[7];
    const float* bh1  = (const float*)d_in[8];
    const float* wih2 = (const float*)d_in[9];
    const float* whh2 = (const float*)d_in[10];
    const float* bi2  = (const float*)d_in[11];
    const float* bh2  = (const float*)d_in[12];
    const float* W1   = (const float*)d_in[13];
    const float* b1   = (const float*)d_in[14];
    const float* W2   = (const float*)d_in[15];
    const float* b2   = (const float*)d_in[16];
    float* out = (float*)d_out;

    char* ws = (char*)d_ws;
    half_t* P    = (half_t*)ws;                               // 134,217,728 B
    half_t* W16  = (half_t*)(ws + 134217728);                 //   2,621,440 B
    float*  bias = (float*)(ws + 134217728 + 2621440);        //       6,144 B

    // dynamic-LDS opt-in (>64 KB); idempotent, not a stream op
    hipFuncSetAttribute((const void*)k_scan7,
                        hipFuncAttributeMaxDynamicSharedMemorySize, 92160);
    hipFuncSetAttribute((const void*)k_proj,
                        hipFuncAttributeMaxDynamicSharedMemorySize, 66560);

    k_cvt<<<5126, 256, 0, stream>>>(whh0, whh1, whh2, wih1, wih2,
                                    bi0, bh0, bi1, bh1, bi2, bh2, W16, bias);
    k_xp0<<<4096, 256, 0, stream>>>(x, wih0, bias, P);
    k_scan7<<<128, 512, 92160, stream>>>(P, W16 + 0 * WN);
    k_proj<<<2048, 256, 66560, stream>>>(P, W16 + 3 * WN, bias + 512);
    k_scan7<<<128, 512, 92160, stream>>>(P, W16 + 1 * WN);
    k_proj<<<2048, 256, 66560, stream>>>(P, W16 + 4 * WN, bias + 1024);
    k_scan7<<<128, 512, 92160, stream>>>(P, W16 + 2 * WN);
    k_head<<<128, 256, 0, stream>>>(P, W1, b1, W2, b2, out);
}